// Round 2
// baseline (1034.137 us; speedup 1.0000x reference)
//
#include <hip/hip_runtime.h>

#define SHFL16(v, k) __shfl((v), (k), 16)
#define FENCE() asm volatile("" ::: "memory")

// per-item LDS layout (dwords), stride 712 (== 8 mod 32 -> the 4 lockstep
// groups of a wave read disjoint bank quartets on uniform b128 broadcasts)
#define STR     712
#define OFF_M1    0   // P, then Pp, then Pn   (15 rows x 16)
#define OFF_M2  240   // A, then IKC           (15 rows x 16)
#define OFF_C   480   // C                     (6 rows x 16)
#define OFF_S4  576   // B -> PpCt -> K        (15 rows x 8)
#define OFF_XP  696   // xp staging            (15)

__device__ __forceinline__ float dot15(const float* Lr, const float* v) {
    float4 x0 = *(const float4*)(Lr);
    float4 x1 = *(const float4*)(Lr + 4);
    float4 x2 = *(const float4*)(Lr + 8);
    float4 x3 = *(const float4*)(Lr + 12);
    return v[0]*x0.x + v[1]*x0.y + v[2]*x0.z + v[3]*x0.w
         + v[4]*x1.x + v[5]*x1.y + v[6]*x1.z + v[7]*x1.w
         + v[8]*x2.x + v[9]*x2.y + v[10]*x2.z + v[11]*x2.w
         + v[12]*x3.x + v[13]*x3.y + v[14]*x3.z;
}

__device__ __forceinline__ void axpy15(const float* Lr, float s, float* acc) {
    float4 x0 = *(const float4*)(Lr);
    float4 x1 = *(const float4*)(Lr + 4);
    float4 x2 = *(const float4*)(Lr + 8);
    float4 x3 = *(const float4*)(Lr + 12);
    acc[0]  += s*x0.x; acc[1]  += s*x0.y; acc[2]  += s*x0.z; acc[3]  += s*x0.w;
    acc[4]  += s*x1.x; acc[5]  += s*x1.y; acc[6]  += s*x1.z; acc[7]  += s*x1.w;
    acc[8]  += s*x2.x; acc[9]  += s*x2.y; acc[10] += s*x2.z; acc[11] += s*x2.w;
    acc[12] += s*x3.x; acc[13] += s*x3.y; acc[14] += s*x3.z;
}

__device__ __forceinline__ float dot6(const float* Lr, const float* v) {
    float4 x0 = *(const float4*)(Lr);
    float2 x1 = *(const float2*)(Lr + 4);
    return v[0]*x0.x + v[1]*x0.y + v[2]*x0.z + v[3]*x0.w + v[4]*x1.x + v[5]*x1.y;
}

__device__ __forceinline__ void wrow15(float* Lr, const float* v) {
    *(float4*)(Lr)      = make_float4(v[0], v[1], v[2], v[3]);
    *(float4*)(Lr + 4)  = make_float4(v[4], v[5], v[6], v[7]);
    *(float4*)(Lr + 8)  = make_float4(v[8], v[9], v[10], v[11]);
    *(float4*)(Lr + 12) = make_float4(v[12], v[13], v[14], 0.f);
}

__device__ __forceinline__ void wrow6(float* Lr, const float* v) {
    *(float4*)(Lr)     = make_float4(v[0], v[1], v[2], v[3]);
    *(float2*)(Lr + 4) = make_float2(v[4], v[5]);
}

__global__ __launch_bounds__(256, 3) void ekf_kernel(
    const float* __restrict__ g_state, const float* __restrict__ g_obs,
    const float* __restrict__ g_u,     const float* __restrict__ g_P,
    const float* __restrict__ g_A,     const float* __restrict__ g_B,
    const float* __restrict__ g_C,     const float* __restrict__ g_D,
    const float* __restrict__ g_c1,    const float* __restrict__ g_c2,
    const float* __restrict__ g_Q,     const float* __restrict__ g_R,
    float* __restrict__ o_xp, float* __restrict__ o_Pn, int bn)
{
    __shared__ __align__(16) float lds[16 * STR];
    const int tid  = threadIdx.x;
    const int ib0  = blockIdx.x * 16;                 // first item of block
    const int nIt  = min(16, bn - ib0);               // items in this block

    // ---- coalesced block staging: P, A -> M1/M2; C -> CSH ----
    {
        const float* gp = g_P + (size_t)ib0 * 225;
        const float* ga = g_A + (size_t)ib0 * 225;
        const int lim = nIt * 225;
        for (int i = tid; i < lim; i += 256) {
            int it = i / 225, idx = i - it * 225;
            int r = idx / 15, j = idx - r * 15;
            lds[it * STR + OFF_M1 + r * 16 + j] = gp[i];
        }
        for (int i = tid; i < lim; i += 256) {
            int it = i / 225, idx = i - it * 225;
            int r = idx / 15, j = idx - r * 15;
            lds[it * STR + OFF_M2 + r * 16 + j] = ga[i];
        }
        const float* gc = g_C + (size_t)ib0 * 90;
        const int limc = nIt * 90;
        for (int i = tid; i < limc; i += 256) {
            int it = i / 90, idx = i - it * 90;
            int r = idx / 15, j = idx - r * 15;
            lds[it * STR + OFF_C + r * 16 + j] = gc[i];
        }
    }

    const int g   = tid >> 4;          // group (item) within block
    const int r   = tid & 15;          // row owned by this lane
    const int itc = ib0 + ((g < nIt) ? g : (nIt - 1));   // clamped item
    const int rc  = r < 15 ? r : 14;
    const int rc6 = r < 6 ? r : 5;
    float* L = lds + g * STR;

    // ---- per-lane small loads ----
    float b[6], dd[6], q[6], rr[6];
    {
        const float* Bb = g_B + (size_t)itc * 90 + rc * 6;
        const float* Db = g_D + (size_t)itc * 36 + rc6 * 6;
        const float* Qb = g_Q + (size_t)itc * 36 + rc6 * 6;
        const float* Rb = g_R + (size_t)itc * 36 + rc6 * 6;
        #pragma unroll
        for (int j = 0; j < 6; ++j) { b[j] = Bb[j]; dd[j] = Db[j]; q[j] = Qb[j]; rr[j] = Rb[j]; }
    }
    float x    = g_state[(size_t)itc * 15 + rc];
    float uu   = g_u[(size_t)itc * 6 + rc6];
    float c1v  = g_c1[(size_t)itc * 15 + rc];
    float obsv = g_obs[(size_t)itc * 6 + rc6];
    float c2v  = g_c2[(size_t)itc * 6 + rc6];

    // stage B rows into S4 (read back wide at Pp += Z*B^T)
    if (r < 15) wrow6(L + OFF_S4 + r * 8, b);

    __syncthreads();

    // ---- per-lane rows of A and C from LDS ----
    float a[15], c[15];
    {
        const float* Ar = L + OFF_M2 + rc * 16;
        float4 x0 = *(const float4*)(Ar);     float4 x1 = *(const float4*)(Ar + 4);
        float4 x2 = *(const float4*)(Ar + 8); float4 x3 = *(const float4*)(Ar + 12);
        a[0]=x0.x; a[1]=x0.y; a[2]=x0.z; a[3]=x0.w; a[4]=x1.x; a[5]=x1.y; a[6]=x1.z; a[7]=x1.w;
        a[8]=x2.x; a[9]=x2.y; a[10]=x2.z; a[11]=x2.w; a[12]=x3.x; a[13]=x3.y; a[14]=x3.z;
        const float* Cr = L + OFF_C + rc6 * 16;
        float4 y0 = *(const float4*)(Cr);     float4 y1 = *(const float4*)(Cr + 4);
        float4 y2 = *(const float4*)(Cr + 8); float4 y3 = *(const float4*)(Cr + 12);
        c[0]=y0.x; c[1]=y0.y; c[2]=y0.z; c[3]=y0.w; c[4]=y1.x; c[5]=y1.y; c[6]=y1.z; c[7]=y1.w;
        c[8]=y2.x; c[9]=y2.y; c[10]=y2.z; c[11]=y2.w; c[12]=y3.x; c[13]=y3.y; c[14]=y3.z;
    }

    // ---- xp0 = A x + B u + c1 ; ev = obs - (C x + D u + c2) ----
    float xp = c1v;
    #pragma unroll
    for (int j = 0; j < 15; ++j) xp += a[j] * SHFL16(x, j);
    #pragma unroll
    for (int j = 0; j < 6; ++j)  xp += b[j] * SHFL16(uu, j);
    float ev = obsv - c2v;
    #pragma unroll
    for (int k = 0; k < 15; ++k) ev -= c[k] * SHFL16(x, k);
    #pragma unroll
    for (int k = 0; k < 6; ++k)  ev -= dd[k] * SHFL16(uu, k);

    // ---- Y = A @ P  (P broadcast from M1) ----
    float y[15];
    #pragma unroll
    for (int j = 0; j < 15; ++j) y[j] = 0.f;
    #pragma unroll
    for (int k = 0; k < 15; ++k) axpy15(L + OFF_M1 + k * 16, a[k], y);

    // ---- Pp = Y @ A^T  (A rows broadcast from M2) ----
    float pp[15];
    #pragma unroll
    for (int j = 0; j < 15; ++j) pp[j] = dot15(L + OFF_M2 + j * 16, y);

    // ---- Z = B @ Q (shuffles), Pp += Z @ B^T (B rows broadcast from S4) ----
    {
        float z[6];
        #pragma unroll
        for (int j = 0; j < 6; ++j) z[j] = 0.f;
        #pragma unroll
        for (int k = 0; k < 6; ++k) {
            float bk = b[k];
            #pragma unroll
            for (int j = 0; j < 6; ++j) z[j] += bk * SHFL16(q[j], k);
        }
        #pragma unroll
        for (int j = 0; j < 15; ++j) pp[j] += dot6(L + OFF_S4 + j * 8, z);
    }

    // ---- write Pp rows -> M1 (P dead) ----
    FENCE();
    if (r < 15) wrow15(L + OFF_M1 + r * 16, pp);
    FENCE();

    // ---- PpCt = Pp @ C^T (C rows broadcast) ----
    float ppct[6];
    #pragma unroll
    for (int j = 0; j < 6; ++j) ppct[j] = dot15(L + OFF_C + j * 16, pp);

    // ---- write PpCt rows -> S4 (B dead) ----
    FENCE();
    if (r < 15) wrow6(L + OFF_S4 + r * 8, ppct);
    FENCE();

    // ---- S = C @ PpCt + R  (PpCt rows broadcast), augmented [S | I] ----
    float sm[12];
    #pragma unroll
    for (int j = 0; j < 6; ++j) { sm[j] = rr[j]; sm[6 + j] = (r == j) ? 1.f : 0.f; }
    #pragma unroll
    for (int k = 0; k < 15; ++k) {
        const float* Pk = L + OFF_S4 + k * 8;
        float4 v0 = *(const float4*)(Pk);
        float2 v1 = *(const float2*)(Pk + 4);
        float ck = c[k];
        sm[0] += ck * v0.x; sm[1] += ck * v0.y; sm[2] += ck * v0.z;
        sm[3] += ck * v0.w; sm[4] += ck * v1.x; sm[5] += ck * v1.y;
    }

    // ---- Gauss-Jordan invert S (SPD) ----
    #pragma unroll
    for (int k = 0; k < 6; ++k) {
        float piv = SHFL16(sm[k], k);
        float ip  = 1.f / piv;
        float f   = sm[k];
        #pragma unroll
        for (int j = 0; j < 12; ++j) {
            float prj = SHFL16(sm[j], k) * ip;
            sm[j] = (r == k) ? prj : (sm[j] - f * prj);
        }
    }

    // ---- K = PpCt @ Sinv (shuffles) ----
    float kk[6];
    #pragma unroll
    for (int j = 0; j < 6; ++j) kk[j] = 0.f;
    #pragma unroll
    for (int k = 0; k < 6; ++k) {
        float pk = ppct[k];
        #pragma unroll
        for (int j = 0; j < 6; ++j) kk[j] += pk * SHFL16(sm[6 + j], k);
    }

    // ---- write K rows -> S4 (PpCt dead) ----
    FENCE();
    if (r < 15) wrow6(L + OFF_S4 + r * 8, kk);
    FENCE();

    // ---- xp += K e ----
    #pragma unroll
    for (int j = 0; j < 6; ++j) xp += kk[j] * SHFL16(ev, j);

    // ---- IKC = I - K @ C  (C rows broadcast) ----
    float ikc[15];
    #pragma unroll
    for (int j = 0; j < 15; ++j) ikc[j] = (r == j) ? 1.f : 0.f;
    #pragma unroll
    for (int k = 0; k < 6; ++k) axpy15(L + OFF_C + k * 16, -kk[k], ikc);

    // ---- write IKC rows -> M2 (A dead) ----
    FENCE();
    if (r < 15) wrow15(L + OFF_M2 + r * 16, ikc);
    FENCE();

    // ---- T3 = IKC @ Pp  (Pp rows broadcast from M1) ----
    float t3[15];
    #pragma unroll
    for (int j = 0; j < 15; ++j) t3[j] = 0.f;
    #pragma unroll
    for (int k = 0; k < 15; ++k) axpy15(L + OFF_M1 + k * 16, ikc[k], t3);

    // ---- Pn = T3 @ IKC^T  (IKC rows broadcast from M2) ----
    float pn[15];
    #pragma unroll
    for (int j = 0; j < 15; ++j) pn[j] = dot15(L + OFF_M2 + j * 16, t3);

    // ---- KR = K @ R (shuffles), Pn += KR @ K^T (K rows broadcast) ----
    {
        float kr[6];
        #pragma unroll
        for (int j = 0; j < 6; ++j) kr[j] = 0.f;
        #pragma unroll
        for (int k = 0; k < 6; ++k) {
            float kkk = kk[k];
            #pragma unroll
            for (int j = 0; j < 6; ++j) kr[j] += kkk * SHFL16(rr[j], k);
        }
        #pragma unroll
        for (int j = 0; j < 15; ++j) pn[j] += dot6(L + OFF_S4 + j * 8, kr);
    }

    // ---- stage results: Pn -> M1, xp -> XP ----
    FENCE();
    if (r < 15) {
        wrow15(L + OFF_M1 + r * 16, pn);
        L[OFF_XP + r] = xp;
    }
    __syncthreads();

    // ---- coalesced block stores ----
    {
        float* gpn = o_Pn + (size_t)ib0 * 225;
        const int lim = nIt * 225;
        for (int i = tid; i < lim; i += 256) {
            int it = i / 225, idx = i - it * 225;
            int rw = idx / 15, j = idx - rw * 15;
            gpn[i] = lds[it * STR + OFF_M1 + rw * 16 + j];
        }
        float* gxp = o_xp + (size_t)ib0 * 15;
        const int lim2 = nIt * 15;
        for (int i = tid; i < lim2; i += 256) {
            int it = i / 15, rw = i - it * 15;
            gxp[i] = lds[it * STR + OFF_XP + rw];
        }
    }
}

extern "C" void kernel_launch(void* const* d_in, const int* in_sizes, int n_in,
                              void* d_out, int out_size, void* d_ws, size_t ws_size,
                              hipStream_t stream) {
    const float* g_state = (const float*)d_in[0];
    const float* g_obs   = (const float*)d_in[1];
    const float* g_u     = (const float*)d_in[2];
    const float* g_P     = (const float*)d_in[3];
    const float* g_A     = (const float*)d_in[4];
    const float* g_B     = (const float*)d_in[5];
    const float* g_C     = (const float*)d_in[6];
    const float* g_D     = (const float*)d_in[7];
    const float* g_c1    = (const float*)d_in[8];
    const float* g_c2    = (const float*)d_in[9];
    const float* g_Q     = (const float*)d_in[10];
    const float* g_R     = (const float*)d_in[11];

    const int bn = in_sizes[0] / 15;
    float* o_xp = (float*)d_out;
    float* o_pn = o_xp + (size_t)bn * 15;

    const int blocks = (bn + 15) / 16;   // 16 items per 256-thread block
    ekf_kernel<<<blocks, 256, 0, stream>>>(
        g_state, g_obs, g_u, g_P, g_A, g_B, g_C, g_D, g_c1, g_c2, g_Q, g_R,
        o_xp, o_pn, bn);
}

// Round 3
// 570.645 us; speedup vs baseline: 1.8122x; 1.8122x over previous
//
#include <hip/hip_runtime.h>

#define SHFL16(v, k) __shfl((v), (k), 16)
#define FENCE() asm volatile("" ::: "memory")

// per-item LDS layout (dwords). Row stride 20 for 15-col matrices: bank
// spread {0,20,8,28,16,4,24,12} -> wide row writes are <=2-way conflicts.
// Item stride 840 == 8 (mod 32): the wave's 4 lockstep groups read disjoint
// bank quartets on uniform b128 broadcasts.
#define STR     840
#define OFF_M1    0   // P, then Pp, then Pn   (15 rows x 20)
#define OFF_M2  300   // A, then IKC           (15 rows x 20)
#define OFF_C   600   // C                     (6 rows x 16)
#define OFF_S4  696   // B -> PpCt -> K        (15 rows x 8)
#define OFF_XP  816   // xp staging            (15)

__device__ __forceinline__ float dot15(const float* Lr, const float* v) {
    float4 x0 = *(const float4*)(Lr);
    float4 x1 = *(const float4*)(Lr + 4);
    float4 x2 = *(const float4*)(Lr + 8);
    float4 x3 = *(const float4*)(Lr + 12);
    return v[0]*x0.x + v[1]*x0.y + v[2]*x0.z + v[3]*x0.w
         + v[4]*x1.x + v[5]*x1.y + v[6]*x1.z + v[7]*x1.w
         + v[8]*x2.x + v[9]*x2.y + v[10]*x2.z + v[11]*x2.w
         + v[12]*x3.x + v[13]*x3.y + v[14]*x3.z;
}

__device__ __forceinline__ void axpy15(const float* Lr, float s, float* acc) {
    float4 x0 = *(const float4*)(Lr);
    float4 x1 = *(const float4*)(Lr + 4);
    float4 x2 = *(const float4*)(Lr + 8);
    float4 x3 = *(const float4*)(Lr + 12);
    acc[0]  += s*x0.x; acc[1]  += s*x0.y; acc[2]  += s*x0.z; acc[3]  += s*x0.w;
    acc[4]  += s*x1.x; acc[5]  += s*x1.y; acc[6]  += s*x1.z; acc[7]  += s*x1.w;
    acc[8]  += s*x2.x; acc[9]  += s*x2.y; acc[10] += s*x2.z; acc[11] += s*x2.w;
    acc[12] += s*x3.x; acc[13] += s*x3.y; acc[14] += s*x3.z;
}

__device__ __forceinline__ float dot6(const float* Lr, const float* v) {
    float4 x0 = *(const float4*)(Lr);
    float2 x1 = *(const float2*)(Lr + 4);
    return v[0]*x0.x + v[1]*x0.y + v[2]*x0.z + v[3]*x0.w + v[4]*x1.x + v[5]*x1.y;
}

__device__ __forceinline__ void wrow15(float* Lr, const float* v) {
    *(float4*)(Lr)      = make_float4(v[0], v[1], v[2], v[3]);
    *(float4*)(Lr + 4)  = make_float4(v[4], v[5], v[6], v[7]);
    *(float4*)(Lr + 8)  = make_float4(v[8], v[9], v[10], v[11]);
    *(float4*)(Lr + 12) = make_float4(v[12], v[13], v[14], 0.f);
}

__device__ __forceinline__ void wrow6(float* Lr, const float* v) {
    *(float4*)(Lr)     = make_float4(v[0], v[1], v[2], v[3]);
    *(float2*)(Lr + 4) = make_float2(v[4], v[5]);
}

__global__ __launch_bounds__(256) void ekf_kernel(
    const float* __restrict__ g_state, const float* __restrict__ g_obs,
    const float* __restrict__ g_u,     const float* __restrict__ g_P,
    const float* __restrict__ g_A,     const float* __restrict__ g_B,
    const float* __restrict__ g_C,     const float* __restrict__ g_D,
    const float* __restrict__ g_c1,    const float* __restrict__ g_c2,
    const float* __restrict__ g_Q,     const float* __restrict__ g_R,
    float* __restrict__ o_xp, float* __restrict__ o_Pn, int bn)
{
    __shared__ __align__(16) float lds[16 * STR];
    const int tid  = threadIdx.x;
    const int ib0  = blockIdx.x * 16;                 // first item of block
    const int nIt  = min(16, bn - ib0);               // items in this block

    const int g   = tid >> 4;          // group (item) within block
    const int r   = tid & 15;          // row owned by this lane
    const int itc = ib0 + ((g < nIt) ? g : (nIt - 1));   // clamped item
    const int rc  = r < 15 ? r : 14;
    const int rc6 = r < 6 ? r : 5;
    float* L = lds + g * STR;

    // ---- per-lane small loads (issue before staging to overlap) ----
    float b[6], dd[6], q[6], rr[6];
    {
        const float* Bb = g_B + (size_t)itc * 90 + rc * 6;
        const float* Db = g_D + (size_t)itc * 36 + rc6 * 6;
        const float* Qb = g_Q + (size_t)itc * 36 + rc6 * 6;
        const float* Rb = g_R + (size_t)itc * 36 + rc6 * 6;
        #pragma unroll
        for (int j = 0; j < 6; ++j) { b[j] = Bb[j]; dd[j] = Db[j]; q[j] = Qb[j]; rr[j] = Rb[j]; }
    }
    float x    = g_state[(size_t)itc * 15 + rc];
    float uu   = g_u[(size_t)itc * 6 + rc6];
    float c1v  = g_c1[(size_t)itc * 15 + rc];
    float obsv = g_obs[(size_t)itc * 6 + rc6];
    float c2v  = g_c2[(size_t)itc * 6 + rc6];

    // ---- coalesced block staging: P -> M1, A -> M2, C -> CSH ----
    {
        const float* gp = g_P + (size_t)ib0 * 225;
        const float* ga = g_A + (size_t)ib0 * 225;
        const int lim = nIt * 225;
        for (int i = tid; i < lim; i += 256) {
            int it = i / 225, idx = i - it * 225;
            int rw = idx / 15, j = idx - rw * 15;
            lds[it * STR + OFF_M1 + rw * 20 + j] = gp[i];
        }
        for (int i = tid; i < lim; i += 256) {
            int it = i / 225, idx = i - it * 225;
            int rw = idx / 15, j = idx - rw * 15;
            lds[it * STR + OFF_M2 + rw * 20 + j] = ga[i];
        }
        const float* gc = g_C + (size_t)ib0 * 90;
        const int limc = nIt * 90;
        for (int i = tid; i < limc; i += 256) {
            int it = i / 90, idx = i - it * 90;
            int rw = idx / 15, j = idx - rw * 15;
            lds[it * STR + OFF_C + rw * 16 + j] = gc[i];
        }
    }

    // stage B rows into S4 (read back wide at Pp += Z*B^T)
    if (r < 15) wrow6(L + OFF_S4 + r * 8, b);

    __syncthreads();

    // ---- per-lane rows of A and C from LDS ----
    float a[15], c[15];
    {
        const float* Ar = L + OFF_M2 + rc * 20;
        float4 x0 = *(const float4*)(Ar);     float4 x1 = *(const float4*)(Ar + 4);
        float4 x2 = *(const float4*)(Ar + 8); float4 x3 = *(const float4*)(Ar + 12);
        a[0]=x0.x; a[1]=x0.y; a[2]=x0.z; a[3]=x0.w; a[4]=x1.x; a[5]=x1.y; a[6]=x1.z; a[7]=x1.w;
        a[8]=x2.x; a[9]=x2.y; a[10]=x2.z; a[11]=x2.w; a[12]=x3.x; a[13]=x3.y; a[14]=x3.z;
        const float* Cr = L + OFF_C + rc6 * 16;
        float4 y0 = *(const float4*)(Cr);     float4 y1 = *(const float4*)(Cr + 4);
        float4 y2 = *(const float4*)(Cr + 8); float4 y3 = *(const float4*)(Cr + 12);
        c[0]=y0.x; c[1]=y0.y; c[2]=y0.z; c[3]=y0.w; c[4]=y1.x; c[5]=y1.y; c[6]=y1.z; c[7]=y1.w;
        c[8]=y2.x; c[9]=y2.y; c[10]=y2.z; c[11]=y2.w; c[12]=y3.x; c[13]=y3.y; c[14]=y3.z;
    }

    // ---- xp0 = A x + B u + c1 ; ev = obs - (C x + D u + c2) ----
    float xp = c1v;
    #pragma unroll
    for (int j = 0; j < 15; ++j) xp += a[j] * SHFL16(x, j);
    #pragma unroll
    for (int j = 0; j < 6; ++j)  xp += b[j] * SHFL16(uu, j);
    float ev = obsv - c2v;
    #pragma unroll
    for (int k = 0; k < 15; ++k) ev -= c[k] * SHFL16(x, k);
    #pragma unroll
    for (int k = 0; k < 6; ++k)  ev -= dd[k] * SHFL16(uu, k);

    // ---- Y = A @ P  (P rows broadcast from M1) ----
    float y[15];
    #pragma unroll
    for (int j = 0; j < 15; ++j) y[j] = 0.f;
    #pragma unroll
    for (int k = 0; k < 15; ++k) axpy15(L + OFF_M1 + k * 20, a[k], y);

    // ---- Pp = Y @ A^T  (A rows broadcast from M2) ----
    float pp[15];
    #pragma unroll
    for (int j = 0; j < 15; ++j) pp[j] = dot15(L + OFF_M2 + j * 20, y);

    // ---- Z = B @ Q (shuffles), Pp += Z @ B^T (B rows broadcast from S4) ----
    {
        float z[6];
        #pragma unroll
        for (int j = 0; j < 6; ++j) z[j] = 0.f;
        #pragma unroll
        for (int k = 0; k < 6; ++k) {
            float bk = b[k];
            #pragma unroll
            for (int j = 0; j < 6; ++j) z[j] += bk * SHFL16(q[j], k);
        }
        #pragma unroll
        for (int j = 0; j < 15; ++j) pp[j] += dot6(L + OFF_S4 + j * 8, z);
    }

    // ---- write Pp rows -> M1 (P dead) ----
    FENCE();
    if (r < 15) wrow15(L + OFF_M1 + r * 20, pp);
    FENCE();

    // ---- PpCt = Pp @ C^T (C rows broadcast) ----
    float ppct[6];
    #pragma unroll
    for (int j = 0; j < 6; ++j) ppct[j] = dot15(L + OFF_C + j * 16, pp);

    // ---- write PpCt rows -> S4 (B dead) ----
    FENCE();
    if (r < 15) wrow6(L + OFF_S4 + r * 8, ppct);
    FENCE();

    // ---- S = C @ PpCt + R  (PpCt rows broadcast), augmented [S | I] ----
    float sm[12];
    #pragma unroll
    for (int j = 0; j < 6; ++j) { sm[j] = rr[j]; sm[6 + j] = (r == j) ? 1.f : 0.f; }
    #pragma unroll
    for (int k = 0; k < 15; ++k) {
        const float* Pk = L + OFF_S4 + k * 8;
        float4 v0 = *(const float4*)(Pk);
        float2 v1 = *(const float2*)(Pk + 4);
        float ck = c[k];
        sm[0] += ck * v0.x; sm[1] += ck * v0.y; sm[2] += ck * v0.z;
        sm[3] += ck * v0.w; sm[4] += ck * v1.x; sm[5] += ck * v1.y;
    }

    // ---- Gauss-Jordan invert S (SPD -> no pivoting) ----
    #pragma unroll
    for (int k = 0; k < 6; ++k) {
        float piv = SHFL16(sm[k], k);
        float ip  = 1.f / piv;
        float f   = sm[k];
        #pragma unroll
        for (int j = 0; j < 12; ++j) {
            float prj = SHFL16(sm[j], k) * ip;
            sm[j] = (r == k) ? prj : (sm[j] - f * prj);
        }
    }

    // ---- K = PpCt @ Sinv (shuffles) ----
    float kk[6];
    #pragma unroll
    for (int j = 0; j < 6; ++j) kk[j] = 0.f;
    #pragma unroll
    for (int k = 0; k < 6; ++k) {
        float pk = ppct[k];
        #pragma unroll
        for (int j = 0; j < 6; ++j) kk[j] += pk * SHFL16(sm[6 + j], k);
    }

    // ---- write K rows -> S4 (PpCt dead) ----
    FENCE();
    if (r < 15) wrow6(L + OFF_S4 + r * 8, kk);
    FENCE();

    // ---- xp += K e ----
    #pragma unroll
    for (int j = 0; j < 6; ++j) xp += kk[j] * SHFL16(ev, j);

    // ---- IKC = I - K @ C  (C rows broadcast) ----
    float ikc[15];
    #pragma unroll
    for (int j = 0; j < 15; ++j) ikc[j] = (r == j) ? 1.f : 0.f;
    #pragma unroll
    for (int k = 0; k < 6; ++k) axpy15(L + OFF_C + k * 16, -kk[k], ikc);

    // ---- write IKC rows -> M2 (A dead) ----
    FENCE();
    if (r < 15) wrow15(L + OFF_M2 + r * 20, ikc);
    FENCE();

    // ---- T3 = IKC @ Pp  (Pp rows broadcast from M1) ----
    float t3[15];
    #pragma unroll
    for (int j = 0; j < 15; ++j) t3[j] = 0.f;
    #pragma unroll
    for (int k = 0; k < 15; ++k) axpy15(L + OFF_M1 + k * 20, ikc[k], t3);

    // ---- Pn = T3 @ IKC^T  (IKC rows broadcast from M2) ----
    float pn[15];
    #pragma unroll
    for (int j = 0; j < 15; ++j) pn[j] = dot15(L + OFF_M2 + j * 20, t3);

    // ---- KR = K @ R (shuffles), Pn += KR @ K^T (K rows broadcast) ----
    {
        float kr[6];
        #pragma unroll
        for (int j = 0; j < 6; ++j) kr[j] = 0.f;
        #pragma unroll
        for (int k = 0; k < 6; ++k) {
            float kkk = kk[k];
            #pragma unroll
            for (int j = 0; j < 6; ++j) kr[j] += kkk * SHFL16(rr[j], k);
        }
        #pragma unroll
        for (int j = 0; j < 15; ++j) pn[j] += dot6(L + OFF_S4 + j * 8, kr);
    }

    // ---- stage results: Pn -> M1, xp -> XP ----
    FENCE();
    if (r < 15) {
        wrow15(L + OFF_M1 + r * 20, pn);
        L[OFF_XP + r] = xp;
    }
    __syncthreads();

    // ---- coalesced block stores ----
    {
        float* gpn = o_Pn + (size_t)ib0 * 225;
        const int lim = nIt * 225;
        for (int i = tid; i < lim; i += 256) {
            int it = i / 225, idx = i - it * 225;
            int rw = idx / 15, j = idx - rw * 15;
            gpn[i] = lds[it * STR + OFF_M1 + rw * 20 + j];
        }
        float* gxp = o_xp + (size_t)ib0 * 15;
        const int lim2 = nIt * 15;
        for (int i = tid; i < lim2; i += 256) {
            int it = i / 15, rw = i - it * 15;
            gxp[i] = lds[it * STR + OFF_XP + rw];
        }
    }
}

extern "C" void kernel_launch(void* const* d_in, const int* in_sizes, int n_in,
                              void* d_out, int out_size, void* d_ws, size_t ws_size,
                              hipStream_t stream) {
    const float* g_state = (const float*)d_in[0];
    const float* g_obs   = (const float*)d_in[1];
    const float* g_u     = (const float*)d_in[2];
    const float* g_P     = (const float*)d_in[3];
    const float* g_A     = (const float*)d_in[4];
    const float* g_B     = (const float*)d_in[5];
    const float* g_C     = (const float*)d_in[6];
    const float* g_D     = (const float*)d_in[7];
    const float* g_c1    = (const float*)d_in[8];
    const float* g_c2    = (const float*)d_in[9];
    const float* g_Q     = (const float*)d_in[10];
    const float* g_R     = (const float*)d_in[11];

    const int bn = in_sizes[0] / 15;
    float* o_xp = (float*)d_out;
    float* o_pn = o_xp + (size_t)bn * 15;

    const int blocks = (bn + 15) / 16;   // 16 items per 256-thread block
    ekf_kernel<<<blocks, 256, 0, stream>>>(
        g_state, g_obs, g_u, g_P, g_A, g_B, g_C, g_D, g_c1, g_c2, g_Q, g_R,
        o_xp, o_pn, bn);
}